// Round 1
// baseline (2639.463 us; speedup 1.0000x reference)
//
#include <hip/hip_runtime.h>

// Involution: fused kernel-generation + 7x7 depthwise involution.
// Shapes (fixed by reference): x (B,256,64,64) f32, reduce_w (64,256),
// bn_* (64,), kproj_w (12544,64), kproj_b (12544,). out (B,256,64,64) f32.

#define C_    256
#define HID_  64
#define KS_   7
#define KK_   49
#define G_    256
#define H_    64
#define W_    64
#define HW_   4096
#define GRP_TILE 32
#define PAD_  4

__global__ __launch_bounds__(256, 2) void invol_fused(
    const float* __restrict__ x,
    const float* __restrict__ reduce_w,
    const float* __restrict__ bn_gamma,
    const float* __restrict__ bn_beta,
    const float* __restrict__ bn_mean,
    const float* __restrict__ bn_var,
    const float* __restrict__ kw,
    const float* __restrict__ kb,
    float* __restrict__ out)
{
    // Transposed reduce_w: rwT[k][o] = reduce_w[o][k]. Row stride 68 floats
    // (272 B, 16B-aligned for b128 broadcast reads).
    __shared__ float rwT[C_][HID_ + PAD_];
    __shared__ float bns[HID_];
    __shared__ float bnb[HID_];

    const int tid = threadIdx.x;
    const int b  = blockIdx.z;
    const int g0 = blockIdx.y * GRP_TILE;
    const int p  = blockIdx.x * 256 + tid;   // pixel index in HW
    const int py = p >> 6;
    const int px = p & 63;

    // ---- stage reduce_w transposed (coalesced global reads) ----
    #pragma unroll 1
    for (int o = 0; o < HID_; ++o) {
        rwT[tid][o] = reduce_w[o * C_ + tid];   // tid = k
    }
    if (tid < HID_) {
        float inv = bn_gamma[tid] * rsqrtf(bn_var[tid] + 1e-5f);
        bns[tid] = inv;
        bnb[tid] = bn_beta[tid] - bn_mean[tid] * inv;
    }
    __syncthreads();

    // ---- per-pixel hidden vector: hv[o] = relu(bn(sum_k x[k]*W[o][k])) ----
    float hv[HID_];
    #pragma unroll
    for (int o = 0; o < HID_; ++o) hv[o] = 0.f;

    const float* xb = x + (size_t)b * C_ * HW_ + p;
    #pragma unroll 4
    for (int k = 0; k < C_; ++k) {
        float xk = xb[(size_t)k * HW_];                 // coalesced across lanes
        const float4* wr = (const float4*)&rwT[k][0];   // broadcast LDS reads
        #pragma unroll
        for (int o4 = 0; o4 < HID_ / 4; ++o4) {
            float4 w = wr[o4];
            hv[o4*4+0] = fmaf(xk, w.x, hv[o4*4+0]);
            hv[o4*4+1] = fmaf(xk, w.y, hv[o4*4+1]);
            hv[o4*4+2] = fmaf(xk, w.z, hv[o4*4+2]);
            hv[o4*4+3] = fmaf(xk, w.w, hv[o4*4+3]);
        }
    }
    #pragma unroll
    for (int o = 0; o < HID_; ++o) {
        hv[o] = fmaxf(fmaf(hv[o], bns[o], bnb[o]), 0.f);
    }

    // ---- per group: 49 taps -> normalize -> involution ----
    #pragma unroll 1
    for (int gi = 0; gi < GRP_TILE; ++gi) {
        const int g = g0 + gi;
        const float* __restrict__ kwg = kw + (size_t)g * KK_ * HID_;
        const float* __restrict__ kbg = kb + (size_t)g * KK_;

        float acc[KK_];
        #pragma unroll
        for (int t = 0; t < KK_; ++t) {
            float a = kbg[t];
            const float4* row = (const float4*)(kwg + t * HID_);
            #pragma unroll
            for (int k4 = 0; k4 < HID_ / 4; ++k4) {
                float4 w = row[k4];
                a = fmaf(w.x, hv[k4*4+0], a);
                a = fmaf(w.y, hv[k4*4+1], a);
                a = fmaf(w.z, hv[k4*4+2], a);
                a = fmaf(w.w, hv[k4*4+3], a);
            }
            acc[t] = a;
        }

        // zero-mean + L2 norm over the 49 taps (scale folded into epilogue)
        float mean = 0.f;
        #pragma unroll
        for (int t = 0; t < KK_; ++t) mean += acc[t];
        mean *= (1.f / 49.f);
        float ss = 0.f;
        #pragma unroll
        for (int t = 0; t < KK_; ++t) {
            acc[t] -= mean;
            ss = fmaf(acc[t], acc[t], ss);
        }
        float inv = 1.f / fmaxf(sqrtf(ss), 1e-6f);

        // 7x7 involution with zero padding
        const float* __restrict__ xg = x + ((size_t)(b * G_ + g)) * HW_;
        float oacc = 0.f;
        #pragma unroll
        for (int i = 0; i < KS_; ++i) {
            int y = py + i - 3;
            bool rok = ((unsigned)y < (unsigned)H_);
            const float* xrow = xg + y * W_;
            #pragma unroll
            for (int j = 0; j < KS_; ++j) {
                int xx = px + j - 3;
                bool ok = rok && ((unsigned)xx < (unsigned)W_);
                float v = ok ? xrow[xx] : 0.f;
                oacc = fmaf(v, acc[i*7+j], oacc);
            }
        }
        out[((size_t)(b * G_ + g)) * HW_ + p] = oacc * inv;
    }
}

extern "C" void kernel_launch(void* const* d_in, const int* in_sizes, int n_in,
                              void* d_out, int out_size, void* d_ws, size_t ws_size,
                              hipStream_t stream) {
    const float* x        = (const float*)d_in[0];
    const float* reduce_w = (const float*)d_in[1];
    const float* bn_gamma = (const float*)d_in[2];
    const float* bn_beta  = (const float*)d_in[3];
    const float* bn_mean  = (const float*)d_in[4];
    const float* bn_var   = (const float*)d_in[5];
    const float* kproj_w  = (const float*)d_in[6];
    const float* kproj_b  = (const float*)d_in[7];
    float* out = (float*)d_out;

    const int B = in_sizes[0] / (C_ * HW_);

    dim3 grid(HW_ / 256, G_ / GRP_TILE, B);
    dim3 block(256);
    invol_fused<<<grid, block, 0, stream>>>(x, reduce_w, bn_gamma, bn_beta,
                                            bn_mean, bn_var, kproj_w, kproj_b, out);
}